// Round 2
// baseline (612.491 us; speedup 1.0000x reference)
//
#include <hip/hip_runtime.h>

// Reference collapses exactly: out[b,t,h*A+a] = X[b,t,h] * (t>0 ? 1 : 0).
// (w_avg = se_excl/where(se_excl==0,1,se_excl) is the indicator {t>0}; e>0
// always, no underflow for this distribution.) Pure memory movement:
// 128 MiB read + 512 MiB write -> write-bound, roofline ~85-107 us.
//
// This round: nontemporal streaming stores (out is write-once, never read),
// float4 X loads redistributed via LDS so stores stay 16B/lane coalesced,
// 8192 blocks x 4-tile grid-stride.

#define NB 64
#define NT 2048
#define NH 256
#define N_ELEM (NB * NT * NH)     // 33,554,432 floats in X
#define TPB 256
#define TILE 1024                 // X floats per tile = TPB float4 loads
#define NTILES (N_ELEM / TILE)    // 32,768
#define NBLOCKS 8192              // 4 tiles per block

using f32x4 = __attribute__((ext_vector_type(4))) float;

__global__ __launch_bounds__(TPB) void attn_bcast_kernel(
    const f32x4* __restrict__ X4,  // X viewed as float4 [N_ELEM/4]
    f32x4* __restrict__ out4)      // out viewed as float4 [N_ELEM]
{
    __shared__ float lds[TILE];

    for (int tile = blockIdx.x; tile < NTILES; tile += NBLOCKS) {
        const int base = tile * TILE;

        // Vector-load 4 KiB of X per block: 16 B/lane, fully coalesced.
        f32x4 x = X4[(base >> 2) + threadIdx.x];
        ((f32x4*)lds)[threadIdx.x] = x;
        __syncthreads();

        // Each thread emits 4 splat-float4 stores, lane-consecutive (16 B/lane
        // coalesced), streaming past L2 via nt.
        #pragma unroll
        for (int k = 0; k < 4; ++k) {
            const int g = base + k * TPB + (int)threadIdx.x;  // X element index
            float v = lds[k * TPB + threadIdx.x];
            // t = (g / NH) % NT ; NH=256 -> >>8 ; NT=2048 -> &2047. Zero t==0.
            if (((unsigned)g >> 8 & 2047u) == 0u) v = 0.0f;
            f32x4 val = {v, v, v, v};
            __builtin_nontemporal_store(val, &out4[g]);
        }
        __syncthreads();  // protect lds before next tile's overwrite
    }
}

extern "C" void kernel_launch(void* const* d_in, const int* in_sizes, int n_in,
                              void* d_out, int out_size, void* d_ws, size_t ws_size,
                              hipStream_t stream) {
    const f32x4* X4 = (const f32x4*)d_in[0];  // [B,T,H] float32
    // d_in[1..4] (W1,b1,W2,b2) unused: prefix-softmax weight == indicator(t>0).
    f32x4* out4 = (f32x4*)d_out;              // [B,T,H*A] as N_ELEM float4s

    attn_bcast_kernel<<<dim3(NBLOCKS), dim3(TPB), 0, stream>>>(X4, out4);
}